// Round 15
// baseline (81.062 us; speedup 1.0000x reference)
//
#include <hip/hip_runtime.h>
#include <hip/hip_bf16.h>
#include <math.h>

#define NA 5000
#define NE 100000
#define F 128
#define KB 16
#define RCUT 5.0f
#define RECW 28   // words per edge record: i1, ux,uy,uz, 24 bf16-pair words
#define QCAP 40   // per-atom index bucket capacity (mean active deg ~6)

typedef long long i64;
typedef __attribute__((ext_vector_type(8))) short bf16x8;   // 8 bf16 = 4 VGPRs
typedef __attribute__((ext_vector_type(4))) float f32x4;

__device__ __forceinline__ float swish_f(float t, float a, float b){
    return a * t / (1.0f + __expf(-b * t));
}
__device__ __forceinline__ float bf2f(unsigned short u){
    return __uint_as_float(((unsigned)u) << 16);
}
__device__ __forceinline__ unsigned short f2bf(float x){
    unsigned b = __float_as_uint(x);
    return (unsigned short)((b + 0x8000u) >> 16);
}
__device__ __forceinline__ unsigned pack2(float a, float b){
    return (unsigned)f2bf(a) | ((unsigned)f2bf(b) << 16);
}
// XOR swizzle for row-major [R][128] bf16 LDS tile (256 B/row).
__device__ __forceinline__ int swz(int row, int byte_in_row){
    return row * 256 + (byte_in_row ^ ((row & 7) << 4));
}

// ---------------------------------------------------------------------------
// MFMA GEMM stage (bf16 weights): acc += act(MT*16 x 128, LDS swizzled) x W^T
// ---------------------------------------------------------------------------
template<int MT>
__device__ __forceinline__ void gemm_stage(const unsigned short* __restrict__ Wb,
                                           const short* act_lds, f32x4 (&acc)[MT][2],
                                           int lane, int wave)
{
    bf16x8 B[2][4], A[MT][4];
    const int cl = lane & 15, kh = lane >> 4;
    #pragma unroll
    for (int ntl = 0; ntl < 2; ++ntl){
        const unsigned short* wp = Wb + (i64)(wave * 32 + ntl * 16 + cl) * F + kh * 8;
        #pragma unroll
        for (int kb = 0; kb < 4; ++kb)
            B[ntl][kb] = *(const bf16x8*)(wp + kb * 32);
    }
    #pragma unroll
    for (int mt = 0; mt < MT; ++mt){
        int row = mt * 16 + cl;
        #pragma unroll
        for (int kb = 0; kb < 4; ++kb)
            A[mt][kb] = *(const bf16x8*)((const char*)act_lds + swz(row, kb * 64 + kh * 16));
    }
    #pragma unroll
    for (int mt = 0; mt < MT; ++mt)
        #pragma unroll
        for (int ntl = 0; ntl < 2; ++ntl)
            #pragma unroll
            for (int kb = 0; kb < 4; ++kb)
                acc[mt][ntl] = __builtin_amdgcn_mfma_f32_16x16x32_bf16(
                    A[mt][kb], B[ntl][kb], acc[mt][ntl], 0, 0, 0);
}

// epilogue (M=32): z = acc + bias (+resid), swish -> bf16 -> act_lds
__device__ __forceinline__ void epi_lds(f32x4 acc[2][2], const float* __restrict__ bc,
                                        const float* resid_lds, int use_resid,
                                        float aS, float bS, short* act_lds,
                                        int lane, int wave)
{
    const int cl = lane & 15, r4 = (lane >> 4) * 4;
    #pragma unroll
    for (int ntl = 0; ntl < 2; ++ntl){
        int col = wave * 32 + ntl * 16 + cl;
        float bv = bc[col];
        #pragma unroll
        for (int mt = 0; mt < 2; ++mt){
            #pragma unroll
            for (int j = 0; j < 4; ++j){
                int row = mt * 16 + r4 + j;
                float z = acc[mt][ntl][j] + bv;
                if (use_resid) z += resid_lds[row * 132 + col];
                z = swish_f(z, aS, bS);
                *(short*)((char*)act_lds + swz(row, col * 2)) = (short)f2bf(z);
            }
        }
    }
}

// ---------------------------------------------------------------------------
// Edge-record builder: slot = edge id, idx bucket per owner atom.
// ---------------------------------------------------------------------------
__device__ __forceinline__ void basis16(float r, float g, float fcut, float* b){
    const float C[KB] = {1.f,15.f,105.f,455.f,1365.f,3003.f,5005.f,6435.f,
                         6435.f,5005.f,3003.f,1365.f,455.f,105.f,15.f,1.f};
    float e = __expf(-fmaxf(g, 0.f) * r);
    float one = 1.f - e;
    float ep = 1.f;
    #pragma unroll
    for (int k = 0; k < KB; ++k){ b[k] = C[k] * ep * fcut; ep *= e; }
    float op = 1.f;
    #pragma unroll
    for (int k = KB-1; k >= 0; --k){ b[k] *= op; op *= one; }
}

__device__ __forceinline__ void prep_edge_block(
    int ebid, const float* __restrict__ xyz, const int* __restrict__ nbrs,
    int* __restrict__ fill, int* __restrict__ idx,
    const float* __restrict__ gs, const float* __restrict__ gp,
    const float* __restrict__ gd, float* __restrict__ rec)
{
    int e = ebid * 256 + threadIdx.x;
    if (e >= NE) return;
    int i0 = nbrs[2*e], i1 = nbrs[2*e+1];
    float dx = xyz[3*i1]   - xyz[3*i0];
    float dy = xyz[3*i1+1] - xyz[3*i0+1];
    float dz = xyz[3*i1+2] - xyz[3*i0+2];
    float r2 = dx*dx + dy*dy + dz*dz + 3e-15f;
    float r = sqrtf(r2);
    if (r >= RCUT) return;
    int slot = atomicAdd(&fill[i0], 1);
    if (slot < QCAP) idx[i0 * QCAP + slot] = e;   // slot = edge id
    float* R = rec + (i64)e * RECW;
    float ir = 1.f / r;
    R[0] = __int_as_float(i1);
    R[1] = dx * ir; R[2] = dy * ir; R[3] = dz * ir;
    float fcut = __expf(-r2 / ((RCUT - r) * (RCUT + r)));
    float bs[KB], bp[KB], bd[KB];
    basis16(r, gs[0], fcut, bs);
    basis16(r, gp[0], fcut, bp);
    basis16(r, gd[0], fcut, bd);
    unsigned* RW = (unsigned*)(R + 4);
    #pragma unroll
    for (int k = 0; k < 8; ++k) RW[k]      = pack2(bs[2*k], bs[2*k+1]);
    #pragma unroll
    for (int k = 0; k < 8; ++k) RW[8 + k]  = pack2(bp[2*k], bp[2*k+1]);
    #pragma unroll
    for (int k = 0; k < 8; ++k) RW[16 + k] = pack2(bd[2*k], bd[2*k+1]);
}

// ---------------------------------------------------------------------------
// Fused 3-stage MLP, MFMA core, M=32.
// PREP=1: blockIdx.y >= CH rows run edge-prep instead.
// RESB=1: channel 0 -> f32 out, channels 1..3 -> bf16 resb (gather source).
// ---------------------------------------------------------------------------
template<int S0, int S1, int S2, int ADD2, int ADD3, int ADDPART, int PREP, int CH, int RESB>
__global__ __launch_bounds__(256)
void mlp3_mfma(const float* __restrict__ in, const unsigned short* __restrict__ part,
               const unsigned short* __restrict__ W1b, const float* __restrict__ b1,
               const unsigned short* __restrict__ W2b, const float* __restrict__ b2,
               const unsigned short* __restrict__ W3b, const float* __restrict__ b3,
               float* __restrict__ out, unsigned short* __restrict__ resb,
               const float* __restrict__ sw_a, const float* __restrict__ sw_b, int n,
               const float* __restrict__ xyz, const int* __restrict__ nbrs,
               int* __restrict__ fill, int* __restrict__ idx,
               const float* __restrict__ gs, const float* __restrict__ gp,
               const float* __restrict__ gd, float* __restrict__ rec)
{
    if (PREP && blockIdx.y >= CH){
        int ebid = (blockIdx.y - CH) * gridDim.x + blockIdx.x;
        if (ebid < (NE + 255) / 256)
            prep_edge_block(ebid, xyz, nbrs, fill, idx, gs, gp, gd, rec);
        return;
    }

    __shared__ short act_lds[32 * 128];     // swizzled bf16 activations
    __shared__ float resid_lds[32 * 132];   // padded f32 residual copy
    const int tid = threadIdx.x;
    const int lane = tid & 63, wave = tid >> 6;
    const int c = blockIdx.y;
    const int a0 = blockIdx.x * 32;
    const i64 S = (i64)NA * F;

    const unsigned short* Wc1 = W1b + (i64)c * F * F;
    const unsigned short* Wc2 = W2b + (i64)c * F * F;
    const unsigned short* Wc3 = W3b + (i64)c * F * F;
    const float* bc1 = b1 + c * F;
    const float* bc2 = b2 + c * F;
    const float* bc3 = b3 + c * F;

    { // stage input: resid (f32) (+part) + swish_S0 -> bf16 act
        float aS = sw_a[S0], bS = sw_b[S0];
        #pragma unroll
        for (int it = 0; it < 4; ++it){
            int ch = tid + it * 256;         // 1024 float4-chunks
            int row = ch >> 5, j4 = ch & 31;
            int g = a0 + row;
            float4 v = make_float4(0.f, 0.f, 0.f, 0.f);
            if (g < n){
                v = *(const float4*)(in + (i64)g * F + j4 * 4);
                if (ADDPART){
                    #pragma unroll
                    for (int m = 0; m < 8; ++m){
                        ushort4 u = *(const ushort4*)(part + (i64)m * S + (i64)g * F + j4 * 4);
                        v.x += bf2f(u.x); v.y += bf2f(u.y);
                        v.z += bf2f(u.z); v.w += bf2f(u.w);
                    }
                }
            }
            *(float4*)&resid_lds[row * 132 + j4 * 4] = v;
            uint2 p;
            p.x = pack2(swish_f(v.x, aS, bS), swish_f(v.y, aS, bS));
            p.y = pack2(swish_f(v.z, aS, bS), swish_f(v.w, aS, bS));
            *(uint2*)((char*)act_lds + swz(row, j4 * 8)) = p;
        }
    }
    __syncthreads();

    f32x4 acc[2][2];
    #pragma unroll
    for (int a = 0; a < 2; ++a){ acc[a][0] = (f32x4){0,0,0,0}; acc[a][1] = (f32x4){0,0,0,0}; }
    gemm_stage<2>(Wc1, act_lds, acc, lane, wave);
    __syncthreads();
    epi_lds(acc, bc1, resid_lds, 0, sw_a[S1], sw_b[S1], act_lds, lane, wave);
    __syncthreads();

    #pragma unroll
    for (int a = 0; a < 2; ++a){ acc[a][0] = (f32x4){0,0,0,0}; acc[a][1] = (f32x4){0,0,0,0}; }
    gemm_stage<2>(Wc2, act_lds, acc, lane, wave);
    __syncthreads();
    epi_lds(acc, bc2, resid_lds, ADD2, sw_a[S2], sw_b[S2], act_lds, lane, wave);
    __syncthreads();

    #pragma unroll
    for (int a = 0; a < 2; ++a){ acc[a][0] = (f32x4){0,0,0,0}; acc[a][1] = (f32x4){0,0,0,0}; }
    gemm_stage<2>(Wc3, act_lds, acc, lane, wave);
    {
        const int cl = lane & 15, r4 = (lane >> 4) * 4;
        #pragma unroll
        for (int ntl = 0; ntl < 2; ++ntl){
            int col = wave * 32 + ntl * 16 + cl;
            float bv = bc3[col];
            #pragma unroll
            for (int mt = 0; mt < 2; ++mt){
                #pragma unroll
                for (int j = 0; j < 4; ++j){
                    int row = mt * 16 + r4 + j;
                    int g = a0 + row;
                    if (g >= n) continue;
                    float z = acc[mt][ntl][j] + bv;
                    if (ADD3) z += resid_lds[row * 132 + col];
                    if (RESB && c > 0)
                        resb[(i64)(c - 1) * S + (i64)g * F + col] = f2bf(z);
                    else
                        out[(i64)g * F + col] = z;
                }
            }
        }
    }
}

// ---------------------------------------------------------------------------
// Bilinear, MFMA core (bf16 W), 64-atom tiles: per (tile, m):
// acc1 = M1*Q_m, acc2 = M2*Q_m, part[m] = bf16(acc1 .* acc2). No atomics.
// ---------------------------------------------------------------------------
__global__ __launch_bounds__(256)
void bilinear_mfma(const unsigned short* __restrict__ Q,
                   const unsigned short* __restrict__ P1b, const unsigned short* __restrict__ P2b,
                   const unsigned short* __restrict__ D1b, const unsigned short* __restrict__ D2b,
                   unsigned short* __restrict__ part, int n)
{
    __shared__ short act_lds[64 * 128];
    const int tid = threadIdx.x;
    const int lane = tid & 63, wave = tid >> 6;
    const int m = blockIdx.y;
    const int a0 = blockIdx.x * 64;
    const i64 S = (i64)NA * F;
    const unsigned short* M1 = (m < 3) ? P1b : D1b;
    const unsigned short* M2 = (m < 3) ? P2b : D2b;
    const unsigned short* A = Q + (i64)m * S;

    #pragma unroll
    for (int it = 0; it < 4; ++it){
        int ch = tid + it * 256;          // 1024 16B-chunks
        int row = ch >> 4, o16 = ch & 15;
        int g = a0 + row;
        uint4 v = make_uint4(0u, 0u, 0u, 0u);
        if (g < n) v = *(const uint4*)(A + (i64)g * F + o16 * 8);
        *(uint4*)((char*)act_lds + swz(row, o16 * 16)) = v;
    }
    __syncthreads();

    f32x4 acc1[4][2], acc2[4][2];
    #pragma unroll
    for (int a = 0; a < 4; ++a){
        acc1[a][0] = (f32x4){0,0,0,0}; acc1[a][1] = (f32x4){0,0,0,0};
        acc2[a][0] = (f32x4){0,0,0,0}; acc2[a][1] = (f32x4){0,0,0,0};
    }
    gemm_stage<4>(M1, act_lds, acc1, lane, wave);
    gemm_stage<4>(M2, act_lds, acc2, lane, wave);

    const int cl = lane & 15, r4 = (lane >> 4) * 4;
    #pragma unroll
    for (int ntl = 0; ntl < 2; ++ntl){
        int col = wave * 32 + ntl * 16 + cl;
        #pragma unroll
        for (int mt = 0; mt < 4; ++mt){
            #pragma unroll
            for (int j = 0; j < 4; ++j){
                int g = a0 + mt * 16 + r4 + j;
                if (g >= n) continue;
                part[(i64)m * S + (i64)g * F + col] =
                    f2bf(acc1[mt][ntl][j] * acc2[mt][ntl][j]);
            }
        }
    }
}

// ---------------------------------------------------------------------------
// Weight convert f32 -> bf16 (13 tensors: 10 weights + 3 G tables) + zero fill
// ---------------------------------------------------------------------------
__global__ __launch_bounds__(256)
void wconv(const float* s0, const float* s1, const float* s2, const float* s3,
           const float* s4, const float* s5, const float* s6, const float* s7,
           const float* s8, const float* s9, const float* g0, const float* g1,
           const float* g2, unsigned short* __restrict__ dst,
           int* __restrict__ fillz)
{
    int t = blockIdx.y;
    if (t == 0){
        for (int i = blockIdx.x * 256 + threadIdx.x; i < NA; i += 32 * 256)
            fillz[i] = 0;
    }
    const float* src; i64 off; int sz;
    if      (t == 0){ src = s0; off = 0;      sz = 65536; }
    else if (t == 1){ src = s1; off = 65536;  sz = 65536; }
    else if (t == 2){ src = s2; off = 131072; sz = 65536; }
    else if (t == 3){ src = s3; off = 196608; sz = 16384; }
    else if (t == 4){ src = s4; off = 212992; sz = 16384; }
    else if (t == 5){ src = s5; off = 229376; sz = 16384; }
    else if (t == 6){ src = s6; off = 245760; sz = 16384; }
    else if (t == 7){ src = s7; off = 262144; sz = 16384; }
    else if (t == 8){ src = s8; off = 278528; sz = 16384; }
    else if (t == 9){ src = s9; off = 294912; sz = 16384; }
    else if (t ==10){ src = g0; off = 311296; sz = 2048; }
    else if (t ==11){ src = g1; off = 313344; sz = 2048; }
    else            { src = g2; off = 315392; sz = 2048; }
    unsigned* d = (unsigned*)(dst + off);
    int pairs = sz >> 1;
    for (int p = blockIdx.x * 256 + threadIdx.x; p < pairs; p += gridDim.x * 256)
        d[p] = pack2(src[2 * p], src[2 * p + 1]);
}

// ---------------------------------------------------------------------------
// Moment gather v7: 2 atoms per block, wave-split (waves 0-1 -> atom0,
// waves 2-3 -> atom1). 128 threads per atom, one f each -> NO reduction
// phase. 8-edge MFMA chunks (D 6KB/atom). Both atoms' idx rows contiguous
// (one coalesced load); recs staging for both atoms overlapped.
// ---------------------------------------------------------------------------
__global__ __launch_bounds__(256)
void q_gather(const float* __restrict__ rec, const int* __restrict__ idx,
              const int* __restrict__ fill,
              const float* __restrict__ res0, const unsigned short* __restrict__ resb,
              const unsigned* __restrict__ Gb,   // 3 x [F][8] u32 (packed bf16)
              float* __restrict__ inp, unsigned short* __restrict__ Q)
{
    const int bx = blockIdx.x;
    const int tid = threadIdx.x;
    const int pa = tid >> 7;            // atom slot 0/1
    const int f  = tid & 127;
    const int n  = bx * 2 + pa;
    const int lane = tid & 63;
    const int wv = (tid >> 6) & 1;      // wave within atom (covers 64 f-cols)
    const i64 S = (i64)NA * F;

    __shared__ int   idx_s[2][QCAP];
    __shared__ float recs[2][QCAP * RECW];          // 9 KB
    __shared__ unsigned short D[2][3 * 8 * 128];    // 12 KB

    if (tid < 2 * QCAP) ((int*)idx_s)[tid] = idx[(i64)bx * 2 * QCAP + tid];
    const int cnt0 = min(fill[bx * 2], QCAP);
    const int cnt1 = min(fill[bx * 2 + 1], QCAP);
    __syncthreads();
    for (int w = tid; w < cnt0 * RECW; w += 256){
        int j = w / RECW, o = w - j * RECW;
        recs[0][w] = rec[(i64)idx_s[0][j] * RECW + o];
    }
    for (int w = tid; w < cnt1 * RECW; w += 256){
        int j = w / RECW, o = w - j * RECW;
        recs[1][w] = rec[(i64)idx_s[1][j] * RECW + o];
    }
    __syncthreads();

    const int cnt = pa ? cnt1 : cnt0;
    const int nch = (max(cnt0, cnt1) + 7) >> 3;

    float qs = 0.f;
    float qp0=0.f, qp1=0.f, qp2=0.f;
    float qd0=0.f, qd1=0.f, qd2=0.f, qd3=0.f, qd4=0.f;
    const float s3 = 1.7320508075688772f;
    const int cl = lane & 15, kh = lane >> 4;

    for (int ci = 0; ci < nch; ++ci){
        const int base = ci * 8;
        // --- MFMA bern x G contraction: rows = 8 edges (chunk), cols = f ---
        {
            int er = base + cl; if (er >= QCAP) er = 0;
            bf16x8 A[3];
            #pragma unroll
            for (int ch = 0; ch < 3; ++ch){
                if (kh < 2){
                    const unsigned* bw = (const unsigned*)&recs[pa][er * RECW + 4];
                    union { uint4 u; bf16x8 h; } cv;
                    cv.u = *(const uint4*)(bw + ch * 8 + kh * 4);
                    A[ch] = cv.h;
                } else {
                    A[ch] = (bf16x8){0,0,0,0,0,0,0,0};
                }
            }
            #pragma unroll
            for (int ch = 0; ch < 3; ++ch){
                #pragma unroll
                for (int ct = 0; ct < 4; ++ct){
                    int fc = wv * 64 + ct * 16 + cl;
                    bf16x8 B;
                    if (kh < 2){
                        union { uint4 u; bf16x8 h; } cv;
                        cv.u = *(const uint4*)(Gb + (i64)ch * F * 8 + fc * 8 + kh * 4);
                        B = cv.h;
                    } else {
                        B = (bf16x8){0,0,0,0,0,0,0,0};
                    }
                    f32x4 z = (f32x4){0.f, 0.f, 0.f, 0.f};
                    z = __builtin_amdgcn_mfma_f32_16x16x32_bf16(A[ch], B, z, 0, 0, 0);
                    // C: col = lane&15 (f), row = kh*4 + j (edge). Rows >= 8 unused.
                    if (kh < 2){
                        #pragma unroll
                        for (int j = 0; j < 4; ++j)
                            D[pa][ch * 1024 + (kh * 4 + j) * 128 + fc] = f2bf(z[j]);
                    }
                }
            }
        }
        __syncthreads();

        // --- per-f accumulation with 1-deep resb row prefetch ---
        const int mrec = min(8, cnt - base);   // may be <= 0 for the idle atom
        int j = 0;
        float a1n = 0.f, a2n = 0.f, a3n = 0.f;
        if (j < mrec){
            int i1 = __float_as_int(recs[pa][(base + j) * RECW]);
            a1n = bf2f(resb[(i64)i1 * F + f]);
            a2n = bf2f(resb[S + (i64)i1 * F + f]);
            a3n = bf2f(resb[2 * S + (i64)i1 * F + f]);
        }
        for (; j < mrec; ++j){
            float a1 = a1n, a2 = a2n, a3 = a3n;
            int jn = j + 1;
            if (jn < mrec){
                int i1 = __float_as_int(recs[pa][(base + jn) * RECW]);
                a1n = bf2f(resb[(i64)i1 * F + f]);
                a2n = bf2f(resb[S + (i64)i1 * F + f]);
                a3n = bf2f(resb[2 * S + (i64)i1 * F + f]);
            }
            const float* R = &recs[pa][(base + j) * RECW];
            float ux = R[1], uy = R[2], uz = R[3];
            float ds = bf2f(D[pa][0 * 1024 + j * 128 + f]);
            float dp = bf2f(D[pa][1 * 1024 + j * 128 + f]);
            float dd = bf2f(D[pa][2 * 1024 + j * 128 + f]);
            qs += a1 * ds;
            float tp = a2 * dp;
            qp0 += tp * uy; qp1 += tp * uz; qp2 += tp * ux;
            float td = a3 * dd;
            qd0 += td * (s3 * ux * uy);
            qd1 += td * (s3 * uy * uz);
            qd2 += td * (1.5f * uz * uz - 0.5f);
            qd3 += td * (s3 * ux * uz);
            qd4 += td * (0.5f * s3 * (ux*ux - uy*uy));
        }
        __syncthreads();   // D reuse safety (uniform: nch is block-uniform)
    }

    // direct writes: each thread owns (atom pa, feature f)
    inp[(i64)n * F + f] = res0[(i64)n * F + f] + qs;
    Q[0*S + (i64)n*F + f] = f2bf(qp0);
    Q[1*S + (i64)n*F + f] = f2bf(qp1);
    Q[2*S + (i64)n*F + f] = f2bf(qp2);
    Q[3*S + (i64)n*F + f] = f2bf(qd0);
    Q[4*S + (i64)n*F + f] = f2bf(qd1);
    Q[5*S + (i64)n*F + f] = f2bf(qd2);
    Q[6*S + (i64)n*F + f] = f2bf(qd3);
    Q[7*S + (i64)n*F + f] = f2bf(qd4);
}

// ---------------------------------------------------------------------------
extern "C" void kernel_launch(void* const* d_in, const int* in_sizes, int n_in,
                              void* d_out, int out_size, void* d_ws, size_t ws_size,
                              hipStream_t stream)
{
    const float* xyz     = (const float*)d_in[0];
    const float* x_tilde = (const float*)d_in[1];
    const int*   nbrs    = (const int*)d_in[2];
    const float* rm_W1 = (const float*)d_in[3],  *rm_b1 = (const float*)d_in[4];
    const float* rm_W2 = (const float*)d_in[5],  *rm_b2 = (const float*)d_in[6];
    const float* rm_W3 = (const float*)d_in[7],  *rm_b3 = (const float*)d_in[8];
    const float* rl_W1 = (const float*)d_in[9],  *rl_b1 = (const float*)d_in[10];
    const float* rl_W2 = (const float*)d_in[11], *rl_b2 = (const float*)d_in[12];
    const float* rl_W3 = (const float*)d_in[13], *rl_b3 = (const float*)d_in[14];
    const float* G_s = (const float*)d_in[15], *G_p = (const float*)d_in[16], *G_d = (const float*)d_in[17];
    const float* P_1 = (const float*)d_in[18], *P_2 = (const float*)d_in[19];
    const float* D_1 = (const float*)d_in[20], *D_2 = (const float*)d_in[21];
    const float* gamma_s = (const float*)d_in[22], *gamma_p = (const float*)d_in[23], *gamma_d = (const float*)d_in[24];
    const float* sw_a = (const float*)d_in[25], *sw_b = (const float*)d_in[26];

    const i64 S = (i64)NA * F;
    float* res0 = (float*)d_ws;                        // S floats (f32 channel 0)
    unsigned short* resb = (unsigned short*)(res0 + S);// 3S ushorts (bf16 ch 1..3)
    float* inp  = (float*)(resb + 3 * S);              // S floats
    unsigned short* Q = (unsigned short*)(inp + S);    // 8S ushorts
    float* rec  = (float*)(Q + 8 * S);                 // NE*RECW floats (aliased by part)
    unsigned short* part = (unsigned short*)rec;       // 8S ushorts <= NE*RECW floats
    int* fill   = (int*)(rec + (i64)NE * RECW);        // NA ints
    int* idx    = fill + NA + 8;                       // NA*QCAP ints
    unsigned short* Wb = (unsigned short*)(idx + NA * QCAP);  // 317440 bf16 (weights+G)

    const int NT = (NA + 31) / 32;   // 157

    // node 1: weights + G tables -> bf16, zero fill[]
    wconv<<<dim3(32, 13), 256, 0, stream>>>(rm_W1, rm_W2, rm_W3, rl_W1, rl_W2, rl_W3,
                                            P_1, P_2, D_1, D_2, G_s, G_p, G_d, Wb, fill);

    // node 2: residual MLP (4 channels, y=0..3; ch0->f32 res0, ch1-3->bf16 resb)
    //         + fused edge-prep (y=4..6)
    mlp3_mfma<0,1,2,1,1,0,1,4,1><<<dim3(NT, 7), 256, 0, stream>>>(
        x_tilde, (const unsigned short*)nullptr,
        Wb + 0, rm_b1, Wb + 65536, rm_b2, Wb + 131072, rm_b3,
        res0, resb, sw_a, sw_b, NA,
        xyz, nbrs, fill, idx, gamma_s, gamma_p, gamma_d, rec);

    // node 3: moments -> inp = res0 + q_s, Q[m] (bf16); 2 atoms/block
    q_gather<<<NA / 2, 256, 0, stream>>>(rec, idx, fill, res0, resb,
                                         (const unsigned*)(Wb + 311296), inp, Q);

    // node 4: bilinear P/D contraction -> part[m] (bf16), 64-atom tiles
    bilinear_mfma<<<dim3((NA + 63) / 64, 8), 256, 0, stream>>>(
        Q, Wb + 245760, Wb + 262144, Wb + 278528, Wb + 294912, part, NA);

    // node 5: final MLP (inp + sum_m part -> out)
    mlp3_mfma<3,4,5,1,0,1,0,1,0><<<dim3(NT, 1), 256, 0, stream>>>(
        inp, part,
        Wb + 196608, rl_b1, Wb + 212992, rl_b2, Wb + 229376, rl_b3,
        (float*)d_out, nullptr, sw_a, sw_b, NA,
        nullptr, nullptr, nullptr, nullptr, nullptr, nullptr, nullptr, nullptr);
}

// Round 16
// 73.537 us; speedup vs baseline: 1.1023x; 1.1023x over previous
//
#include <hip/hip_runtime.h>
#include <hip/hip_bf16.h>
#include <math.h>

#define NA 5000
#define NE 100000
#define F 128
#define KB 16
#define RCUT 5.0f
#define RECW 28   // words per edge record: i1, ux,uy,uz, 24 bf16-pair words
#define QCAP 40   // per-atom index bucket capacity (mean active deg ~6)

typedef long long i64;
typedef __attribute__((ext_vector_type(8))) short bf16x8;   // 8 bf16 = 4 VGPRs
typedef __attribute__((ext_vector_type(4))) float f32x4;

__device__ __forceinline__ float swish_f(float t, float a, float b){
    return a * t / (1.0f + __expf(-b * t));
}
__device__ __forceinline__ float bf2f(unsigned short u){
    return __uint_as_float(((unsigned)u) << 16);
}
__device__ __forceinline__ unsigned short f2bf(float x){
    unsigned b = __float_as_uint(x);
    return (unsigned short)((b + 0x8000u) >> 16);
}
__device__ __forceinline__ unsigned pack2(float a, float b){
    return (unsigned)f2bf(a) | ((unsigned)f2bf(b) << 16);
}
// XOR swizzle for row-major [R][128] bf16 LDS tile (256 B/row).
__device__ __forceinline__ int swz(int row, int byte_in_row){
    return row * 256 + (byte_in_row ^ ((row & 7) << 4));
}

// ---------------------------------------------------------------------------
// MFMA GEMM stage (bf16 weights): acc += act(MT*16 x 128, LDS swizzled) x W^T
// ---------------------------------------------------------------------------
template<int MT>
__device__ __forceinline__ void gemm_stage(const unsigned short* __restrict__ Wb,
                                           const short* act_lds, f32x4 (&acc)[MT][2],
                                           int lane, int wave)
{
    bf16x8 B[2][4], A[MT][4];
    const int cl = lane & 15, kh = lane >> 4;
    #pragma unroll
    for (int ntl = 0; ntl < 2; ++ntl){
        const unsigned short* wp = Wb + (i64)(wave * 32 + ntl * 16 + cl) * F + kh * 8;
        #pragma unroll
        for (int kb = 0; kb < 4; ++kb)
            B[ntl][kb] = *(const bf16x8*)(wp + kb * 32);
    }
    #pragma unroll
    for (int mt = 0; mt < MT; ++mt){
        int row = mt * 16 + cl;
        #pragma unroll
        for (int kb = 0; kb < 4; ++kb)
            A[mt][kb] = *(const bf16x8*)((const char*)act_lds + swz(row, kb * 64 + kh * 16));
    }
    #pragma unroll
    for (int mt = 0; mt < MT; ++mt)
        #pragma unroll
        for (int ntl = 0; ntl < 2; ++ntl)
            #pragma unroll
            for (int kb = 0; kb < 4; ++kb)
                acc[mt][ntl] = __builtin_amdgcn_mfma_f32_16x16x32_bf16(
                    A[mt][kb], B[ntl][kb], acc[mt][ntl], 0, 0, 0);
}

// epilogue: z = acc + bias (+resid), swish -> bf16 -> act_lds
template<int MT>
__device__ __forceinline__ void epi_lds(f32x4 acc[MT][2], const float* __restrict__ bc,
                                        const float* resid_lds, int use_resid,
                                        float aS, float bS, short* act_lds,
                                        int lane, int wave)
{
    const int cl = lane & 15, r4 = (lane >> 4) * 4;
    #pragma unroll
    for (int ntl = 0; ntl < 2; ++ntl){
        int col = wave * 32 + ntl * 16 + cl;
        float bv = bc[col];
        #pragma unroll
        for (int mt = 0; mt < MT; ++mt){
            #pragma unroll
            for (int j = 0; j < 4; ++j){
                int row = mt * 16 + r4 + j;
                float z = acc[mt][ntl][j] + bv;
                if (use_resid) z += resid_lds[row * 132 + col];
                z = swish_f(z, aS, bS);
                *(short*)((char*)act_lds + swz(row, col * 2)) = (short)f2bf(z);
            }
        }
    }
}

// ---------------------------------------------------------------------------
// Edge-record builder: slot = edge id, idx bucket per owner atom.
// ---------------------------------------------------------------------------
__device__ __forceinline__ void basis16(float r, float g, float fcut, float* b){
    const float C[KB] = {1.f,15.f,105.f,455.f,1365.f,3003.f,5005.f,6435.f,
                         6435.f,5005.f,3003.f,1365.f,455.f,105.f,15.f,1.f};
    float e = __expf(-fmaxf(g, 0.f) * r);
    float one = 1.f - e;
    float ep = 1.f;
    #pragma unroll
    for (int k = 0; k < KB; ++k){ b[k] = C[k] * ep * fcut; ep *= e; }
    float op = 1.f;
    #pragma unroll
    for (int k = KB-1; k >= 0; --k){ b[k] *= op; op *= one; }
}

__device__ __forceinline__ void prep_edge_block(
    int ebid, const float* __restrict__ xyz, const int* __restrict__ nbrs,
    int* __restrict__ fill, int* __restrict__ idx,
    const float* __restrict__ gs, const float* __restrict__ gp,
    const float* __restrict__ gd, float* __restrict__ rec)
{
    int e = ebid * 256 + threadIdx.x;
    if (e >= NE) return;
    int i0 = nbrs[2*e], i1 = nbrs[2*e+1];
    float dx = xyz[3*i1]   - xyz[3*i0];
    float dy = xyz[3*i1+1] - xyz[3*i0+1];
    float dz = xyz[3*i1+2] - xyz[3*i0+2];
    float r2 = dx*dx + dy*dy + dz*dz + 3e-15f;
    float r = sqrtf(r2);
    if (r >= RCUT) return;
    int slot = atomicAdd(&fill[i0], 1);
    if (slot < QCAP) idx[i0 * QCAP + slot] = e;   // slot = edge id
    float* R = rec + (i64)e * RECW;
    float ir = 1.f / r;
    R[0] = __int_as_float(i1);
    R[1] = dx * ir; R[2] = dy * ir; R[3] = dz * ir;
    float fcut = __expf(-r2 / ((RCUT - r) * (RCUT + r)));
    float bs[KB], bp[KB], bd[KB];
    basis16(r, gs[0], fcut, bs);
    basis16(r, gp[0], fcut, bp);
    basis16(r, gd[0], fcut, bd);
    unsigned* RW = (unsigned*)(R + 4);
    #pragma unroll
    for (int k = 0; k < 8; ++k) RW[k]      = pack2(bs[2*k], bs[2*k+1]);
    #pragma unroll
    for (int k = 0; k < 8; ++k) RW[8 + k]  = pack2(bp[2*k], bp[2*k+1]);
    #pragma unroll
    for (int k = 0; k < 8; ++k) RW[16 + k] = pack2(bd[2*k], bd[2*k+1]);
}

// ---------------------------------------------------------------------------
// Fused 3-stage MLP (rm path), MFMA core, M=32.
// PREP=1: blockIdx.y >= CH rows run edge-prep instead.
// RESB=1: channel 0 -> f32 out, channels 1..3 -> bf16 resb (gather source).
// ---------------------------------------------------------------------------
template<int S0, int S1, int S2, int ADD2, int ADD3, int PREP, int CH, int RESB>
__global__ __launch_bounds__(256)
void mlp3_mfma(const float* __restrict__ in,
               const unsigned short* __restrict__ W1b, const float* __restrict__ b1,
               const unsigned short* __restrict__ W2b, const float* __restrict__ b2,
               const unsigned short* __restrict__ W3b, const float* __restrict__ b3,
               float* __restrict__ out, unsigned short* __restrict__ resb,
               const float* __restrict__ sw_a, const float* __restrict__ sw_b, int n,
               const float* __restrict__ xyz, const int* __restrict__ nbrs,
               int* __restrict__ fill, int* __restrict__ idx,
               const float* __restrict__ gs, const float* __restrict__ gp,
               const float* __restrict__ gd, float* __restrict__ rec)
{
    if (PREP && blockIdx.y >= CH){
        int ebid = (blockIdx.y - CH) * gridDim.x + blockIdx.x;
        if (ebid < (NE + 255) / 256)
            prep_edge_block(ebid, xyz, nbrs, fill, idx, gs, gp, gd, rec);
        return;
    }

    __shared__ short act_lds[32 * 128];     // swizzled bf16 activations
    __shared__ float resid_lds[32 * 132];   // padded f32 residual copy
    const int tid = threadIdx.x;
    const int lane = tid & 63, wave = tid >> 6;
    const int c = blockIdx.y;
    const int a0 = blockIdx.x * 32;
    const i64 S = (i64)NA * F;

    const unsigned short* Wc1 = W1b + (i64)c * F * F;
    const unsigned short* Wc2 = W2b + (i64)c * F * F;
    const unsigned short* Wc3 = W3b + (i64)c * F * F;
    const float* bc1 = b1 + c * F;
    const float* bc2 = b2 + c * F;
    const float* bc3 = b3 + c * F;

    { // stage input: resid (f32) + swish_S0 -> bf16 act
        float aS = sw_a[S0], bS = sw_b[S0];
        #pragma unroll
        for (int it = 0; it < 4; ++it){
            int ch = tid + it * 256;         // 1024 float4-chunks
            int row = ch >> 5, j4 = ch & 31;
            int g = a0 + row;
            float4 v = make_float4(0.f, 0.f, 0.f, 0.f);
            if (g < n) v = *(const float4*)(in + (i64)g * F + j4 * 4);
            *(float4*)&resid_lds[row * 132 + j4 * 4] = v;
            uint2 p;
            p.x = pack2(swish_f(v.x, aS, bS), swish_f(v.y, aS, bS));
            p.y = pack2(swish_f(v.z, aS, bS), swish_f(v.w, aS, bS));
            *(uint2*)((char*)act_lds + swz(row, j4 * 8)) = p;
        }
    }
    __syncthreads();

    f32x4 acc[2][2];
    #pragma unroll
    for (int a = 0; a < 2; ++a){ acc[a][0] = (f32x4){0,0,0,0}; acc[a][1] = (f32x4){0,0,0,0}; }
    gemm_stage<2>(Wc1, act_lds, acc, lane, wave);
    __syncthreads();
    epi_lds<2>(acc, bc1, resid_lds, 0, sw_a[S1], sw_b[S1], act_lds, lane, wave);
    __syncthreads();

    #pragma unroll
    for (int a = 0; a < 2; ++a){ acc[a][0] = (f32x4){0,0,0,0}; acc[a][1] = (f32x4){0,0,0,0}; }
    gemm_stage<2>(Wc2, act_lds, acc, lane, wave);
    __syncthreads();
    epi_lds<2>(acc, bc2, resid_lds, ADD2, sw_a[S2], sw_b[S2], act_lds, lane, wave);
    __syncthreads();

    #pragma unroll
    for (int a = 0; a < 2; ++a){ acc[a][0] = (f32x4){0,0,0,0}; acc[a][1] = (f32x4){0,0,0,0}; }
    gemm_stage<2>(Wc3, act_lds, acc, lane, wave);
    {
        const int cl = lane & 15, r4 = (lane >> 4) * 4;
        #pragma unroll
        for (int ntl = 0; ntl < 2; ++ntl){
            int col = wave * 32 + ntl * 16 + cl;
            float bv = bc3[col];
            #pragma unroll
            for (int mt = 0; mt < 2; ++mt){
                #pragma unroll
                for (int j = 0; j < 4; ++j){
                    int row = mt * 16 + r4 + j;
                    int g = a0 + row;
                    if (g >= n) continue;
                    float z = acc[mt][ntl][j] + bv;
                    if (ADD3) z += resid_lds[row * 132 + col];
                    if (RESB && c > 0)
                        resb[(i64)(c - 1) * S + (i64)g * F + col] = f2bf(z);
                    else
                        out[(i64)g * F + col] = z;
                }
            }
        }
    }
}

// ---------------------------------------------------------------------------
// Final MLP, M=16 (313 blocks -> ~1.2 blocks/CU): inp + sum_m part ->
// 3-stage rl MLP -> out. gemm_stage<1>, no MFMA waste.
// ---------------------------------------------------------------------------
__global__ __launch_bounds__(256)
void mlpf16(const float* __restrict__ inp, const unsigned short* __restrict__ part,
            const unsigned short* __restrict__ W1b, const float* __restrict__ b1,
            const unsigned short* __restrict__ W2b, const float* __restrict__ b2,
            const unsigned short* __restrict__ W3b, const float* __restrict__ b3,
            float* __restrict__ out,
            const float* __restrict__ sw_a, const float* __restrict__ sw_b, int n)
{
    __shared__ short act_lds[16 * 128];
    __shared__ float resid_lds[16 * 132];
    const int tid = threadIdx.x;
    const int lane = tid & 63, wave = tid >> 6;
    const int a0 = blockIdx.x * 16;
    const i64 S = (i64)NA * F;
    const int cl = lane & 15, r4 = (lane >> 4) * 4;

    { // stage: z = inp + sum_m part -> resid; act = swish_3(z)
        float aS = sw_a[3], bS = sw_b[3];
        #pragma unroll
        for (int it = 0; it < 2; ++it){
            int ch = tid + it * 256;          // 512 float4-chunks
            int row = ch >> 5, j4 = ch & 31;
            int g = a0 + row;
            float4 v = make_float4(0.f, 0.f, 0.f, 0.f);
            if (g < n){
                v = *(const float4*)(inp + (i64)g * F + j4 * 4);
                #pragma unroll
                for (int m = 0; m < 8; ++m){
                    ushort4 u = *(const ushort4*)(part + (i64)m * S + (i64)g * F + j4 * 4);
                    v.x += bf2f(u.x); v.y += bf2f(u.y);
                    v.z += bf2f(u.z); v.w += bf2f(u.w);
                }
            }
            *(float4*)&resid_lds[row * 132 + j4 * 4] = v;
            uint2 p;
            p.x = pack2(swish_f(v.x, aS, bS), swish_f(v.y, aS, bS));
            p.y = pack2(swish_f(v.z, aS, bS), swish_f(v.w, aS, bS));
            *(uint2*)((char*)act_lds + swz(row, j4 * 8)) = p;
        }
    }
    __syncthreads();

    f32x4 acc[1][2];
    acc[0][0] = (f32x4){0,0,0,0}; acc[0][1] = (f32x4){0,0,0,0};
    gemm_stage<1>(W1b, act_lds, acc, lane, wave);
    __syncthreads();
    epi_lds<1>(acc, b1, resid_lds, 0, sw_a[4], sw_b[4], act_lds, lane, wave);
    __syncthreads();

    acc[0][0] = (f32x4){0,0,0,0}; acc[0][1] = (f32x4){0,0,0,0};
    gemm_stage<1>(W2b, act_lds, acc, lane, wave);
    __syncthreads();
    epi_lds<1>(acc, b2, resid_lds, 1, sw_a[5], sw_b[5], act_lds, lane, wave);
    __syncthreads();

    acc[0][0] = (f32x4){0,0,0,0}; acc[0][1] = (f32x4){0,0,0,0};
    gemm_stage<1>(W3b, act_lds, acc, lane, wave);
    {
        #pragma unroll
        for (int ntl = 0; ntl < 2; ++ntl){
            int col = wave * 32 + ntl * 16 + cl;
            float bv = b3[col];
            #pragma unroll
            for (int j = 0; j < 4; ++j){
                int g = a0 + r4 + j;
                if (g >= n) continue;
                out[(i64)g * F + col] = acc[0][ntl][j] + bv;
            }
        }
    }
}

// ---------------------------------------------------------------------------
// Bilinear, MFMA core (bf16 W), 64-atom tiles: per (tile, m):
// acc1 = M1*Q_m, acc2 = M2*Q_m, part[m] = bf16(acc1 .* acc2). No atomics.
// ---------------------------------------------------------------------------
__global__ __launch_bounds__(256)
void bilinear_mfma(const unsigned short* __restrict__ Q,
                   const unsigned short* __restrict__ P1b, const unsigned short* __restrict__ P2b,
                   const unsigned short* __restrict__ D1b, const unsigned short* __restrict__ D2b,
                   unsigned short* __restrict__ part, int n)
{
    __shared__ short act_lds[64 * 128];
    const int tid = threadIdx.x;
    const int lane = tid & 63, wave = tid >> 6;
    const int m = blockIdx.y;
    const int a0 = blockIdx.x * 64;
    const i64 S = (i64)NA * F;
    const unsigned short* M1 = (m < 3) ? P1b : D1b;
    const unsigned short* M2 = (m < 3) ? P2b : D2b;
    const unsigned short* A = Q + (i64)m * S;

    #pragma unroll
    for (int it = 0; it < 4; ++it){
        int ch = tid + it * 256;          // 1024 16B-chunks
        int row = ch >> 4, o16 = ch & 15;
        int g = a0 + row;
        uint4 v = make_uint4(0u, 0u, 0u, 0u);
        if (g < n) v = *(const uint4*)(A + (i64)g * F + o16 * 8);
        *(uint4*)((char*)act_lds + swz(row, o16 * 16)) = v;
    }
    __syncthreads();

    f32x4 acc1[4][2], acc2[4][2];
    #pragma unroll
    for (int a = 0; a < 4; ++a){
        acc1[a][0] = (f32x4){0,0,0,0}; acc1[a][1] = (f32x4){0,0,0,0};
        acc2[a][0] = (f32x4){0,0,0,0}; acc2[a][1] = (f32x4){0,0,0,0};
    }
    gemm_stage<4>(M1, act_lds, acc1, lane, wave);
    gemm_stage<4>(M2, act_lds, acc2, lane, wave);

    const int cl = lane & 15, r4 = (lane >> 4) * 4;
    #pragma unroll
    for (int ntl = 0; ntl < 2; ++ntl){
        int col = wave * 32 + ntl * 16 + cl;
        #pragma unroll
        for (int mt = 0; mt < 4; ++mt){
            #pragma unroll
            for (int j = 0; j < 4; ++j){
                int g = a0 + mt * 16 + r4 + j;
                if (g >= n) continue;
                part[(i64)m * S + (i64)g * F + col] =
                    f2bf(acc1[mt][ntl][j] * acc2[mt][ntl][j]);
            }
        }
    }
}

// ---------------------------------------------------------------------------
// Weight convert f32 -> bf16 (13 tensors: 10 weights + 3 G tables) + zero fill
// ---------------------------------------------------------------------------
__global__ __launch_bounds__(256)
void wconv(const float* s0, const float* s1, const float* s2, const float* s3,
           const float* s4, const float* s5, const float* s6, const float* s7,
           const float* s8, const float* s9, const float* g0, const float* g1,
           const float* g2, unsigned short* __restrict__ dst,
           int* __restrict__ fillz)
{
    int t = blockIdx.y;
    if (t == 0){
        for (int i = blockIdx.x * 256 + threadIdx.x; i < NA; i += 32 * 256)
            fillz[i] = 0;
    }
    const float* src; i64 off; int sz;
    if      (t == 0){ src = s0; off = 0;      sz = 65536; }
    else if (t == 1){ src = s1; off = 65536;  sz = 65536; }
    else if (t == 2){ src = s2; off = 131072; sz = 65536; }
    else if (t == 3){ src = s3; off = 196608; sz = 16384; }
    else if (t == 4){ src = s4; off = 212992; sz = 16384; }
    else if (t == 5){ src = s5; off = 229376; sz = 16384; }
    else if (t == 6){ src = s6; off = 245760; sz = 16384; }
    else if (t == 7){ src = s7; off = 262144; sz = 16384; }
    else if (t == 8){ src = s8; off = 278528; sz = 16384; }
    else if (t == 9){ src = s9; off = 294912; sz = 16384; }
    else if (t ==10){ src = g0; off = 311296; sz = 2048; }
    else if (t ==11){ src = g1; off = 313344; sz = 2048; }
    else            { src = g2; off = 315392; sz = 2048; }
    unsigned* d = (unsigned*)(dst + off);
    int pairs = sz >> 1;
    for (int p = blockIdx.x * 256 + threadIdx.x; p < pairs; p += gridDim.x * 256)
        d[p] = pack2(src[2 * p], src[2 * p + 1]);
}

// ---------------------------------------------------------------------------
// Moment gather v5 (r12/r14 form): block per atom. MFMA bern x G contraction
// per 16-edge chunk, D -> LDS bf16; f-major loop with software-pipelined
// resb row prefetch accumulates the moments.
// ---------------------------------------------------------------------------
__global__ __launch_bounds__(256)
void q_gather(const float* __restrict__ rec, const int* __restrict__ idx,
              const int* __restrict__ fill,
              const float* __restrict__ res0, const unsigned short* __restrict__ resb,
              const unsigned* __restrict__ Gb,   // 3 x [F][8] u32 (packed bf16)
              float* __restrict__ inp, unsigned short* __restrict__ Q)
{
    const int n = blockIdx.x;
    const int tid = threadIdx.x;
    const int s = tid >> 7;
    const int f = tid & 127;
    const int lane = tid & 63, wave = tid >> 6;
    const i64 S = (i64)NA * F;

    __shared__ int   idx_s[QCAP];
    __shared__ float recs[QCAP * RECW];             // 4.5 KB
    __shared__ __align__(16) char upool[12288];     // D (12KB bf16) / red (9.2KB f32)
    unsigned short* D = (unsigned short*)upool;     // [3][16][128]
    float* red = (float*)upool;                     // [2][9][128]

    if (tid < QCAP) idx_s[tid] = idx[n * QCAP + tid];
    const int cnt = min(fill[n], QCAP);
    __syncthreads();
    for (int w = tid; w < cnt * RECW; w += 256){
        int j = w / RECW, o = w - j * RECW;
        recs[w] = rec[(i64)idx_s[j] * RECW + o];
    }
    __syncthreads();

    float qs = 0.f;
    float qp0=0.f, qp1=0.f, qp2=0.f;
    float qd0=0.f, qd1=0.f, qd2=0.f, qd3=0.f, qd4=0.f;
    const float s3 = 1.7320508075688772f;
    const int cl = lane & 15, kh = lane >> 4;

    for (int base = 0; base < cnt; base += 16){
        // --- MFMA bern x G contraction for this chunk ---
        {
            int er = base + cl; if (er >= QCAP) er = 0;   // stay in recs bounds
            bf16x8 A[3];
            #pragma unroll
            for (int ch = 0; ch < 3; ++ch){
                if (kh < 2){
                    const unsigned* bw = (const unsigned*)&recs[er * RECW + 4];
                    union { uint4 u; bf16x8 h; } cv;
                    cv.u = *(const uint4*)(bw + ch * 8 + kh * 4);
                    A[ch] = cv.h;
                } else {
                    A[ch] = (bf16x8){0,0,0,0,0,0,0,0};
                }
            }
            #pragma unroll
            for (int ch = 0; ch < 3; ++ch){
                #pragma unroll
                for (int ct = 0; ct < 2; ++ct){
                    int fc = wave * 32 + ct * 16 + cl;
                    bf16x8 B;
                    if (kh < 2){
                        union { uint4 u; bf16x8 h; } cv;
                        cv.u = *(const uint4*)(Gb + (i64)ch * F * 8 + fc * 8 + kh * 4);
                        B = cv.h;
                    } else {
                        B = (bf16x8){0,0,0,0,0,0,0,0};
                    }
                    f32x4 z = (f32x4){0.f, 0.f, 0.f, 0.f};
                    z = __builtin_amdgcn_mfma_f32_16x16x32_bf16(A[ch], B, z, 0, 0, 0);
                    // C layout: col = lane&15 (f), row = (lane>>4)*4 + j (edge)
                    #pragma unroll
                    for (int j = 0; j < 4; ++j)
                        D[ch * 2048 + (kh * 4 + j) * 128 + fc] = f2bf(z[j]);
                }
            }
        }
        __syncthreads();

        // --- f-major accumulation with 1-deep a-row prefetch ---
        const int mrec = min(16, cnt - base);
        int j = s;
        float a1n = 0.f, a2n = 0.f, a3n = 0.f;
        if (j < mrec){
            int i1 = __float_as_int(recs[(base + j) * RECW]);
            a1n = bf2f(resb[(i64)i1 * F + f]);
            a2n = bf2f(resb[S + (i64)i1 * F + f]);
            a3n = bf2f(resb[2 * S + (i64)i1 * F + f]);
        }
        for (; j < mrec; j += 2){
            float a1 = a1n, a2 = a2n, a3 = a3n;
            int jn = j + 2;
            if (jn < mrec){
                int i1 = __float_as_int(recs[(base + jn) * RECW]);
                a1n = bf2f(resb[(i64)i1 * F + f]);
                a2n = bf2f(resb[S + (i64)i1 * F + f]);
                a3n = bf2f(resb[2 * S + (i64)i1 * F + f]);
            }
            const float* R = &recs[(base + j) * RECW];
            float ux = R[1], uy = R[2], uz = R[3];
            float ds = bf2f(D[0 * 2048 + j * 128 + f]);
            float dp = bf2f(D[1 * 2048 + j * 128 + f]);
            float dd = bf2f(D[2 * 2048 + j * 128 + f]);
            qs += a1 * ds;
            float tp = a2 * dp;
            qp0 += tp * uy; qp1 += tp * uz; qp2 += tp * ux;
            float td = a3 * dd;
            qd0 += td * (s3 * ux * uy);
            qd1 += td * (s3 * uy * uz);
            qd2 += td * (1.5f * uz * uz - 0.5f);
            qd3 += td * (s3 * ux * uz);
            qd4 += td * (0.5f * s3 * (ux*ux - uy*uy));
        }
        __syncthreads();   // D reuse / red aliasing safety
    }

    red[(s * 9 + 0) * 128 + f] = qs;
    red[(s * 9 + 1) * 128 + f] = qp0; red[(s * 9 + 2) * 128 + f] = qp1;
    red[(s * 9 + 3) * 128 + f] = qp2;
    red[(s * 9 + 4) * 128 + f] = qd0; red[(s * 9 + 5) * 128 + f] = qd1;
    red[(s * 9 + 6) * 128 + f] = qd2; red[(s * 9 + 7) * 128 + f] = qd3;
    red[(s * 9 + 8) * 128 + f] = qd4;
    __syncthreads();
    if (s == 0){
        float sums[9];
        #pragma unroll
        for (int i = 0; i < 9; ++i)
            sums[i] = red[(0 * 9 + i) * 128 + f] + red[(1 * 9 + i) * 128 + f];
        inp[(i64)n*F + f] = res0[(i64)n*F + f] + sums[0];
        #pragma unroll
        for (int mm = 0; mm < 8; ++mm)
            Q[(i64)mm * S + (i64)n*F + f] = f2bf(sums[1 + mm]);
    }
}

// ---------------------------------------------------------------------------
extern "C" void kernel_launch(void* const* d_in, const int* in_sizes, int n_in,
                              void* d_out, int out_size, void* d_ws, size_t ws_size,
                              hipStream_t stream)
{
    const float* xyz     = (const float*)d_in[0];
    const float* x_tilde = (const float*)d_in[1];
    const int*   nbrs    = (const int*)d_in[2];
    const float* rm_W1 = (const float*)d_in[3],  *rm_b1 = (const float*)d_in[4];
    const float* rm_W2 = (const float*)d_in[5],  *rm_b2 = (const float*)d_in[6];
    const float* rm_W3 = (const float*)d_in[7],  *rm_b3 = (const float*)d_in[8];
    const float* rl_W1 = (const float*)d_in[9],  *rl_b1 = (const float*)d_in[10];
    const float* rl_W2 = (const float*)d_in[11], *rl_b2 = (const float*)d_in[12];
    const float* rl_W3 = (const float*)d_in[13], *rl_b3 = (const float*)d_in[14];
    const float* G_s = (const float*)d_in[15], *G_p = (const float*)d_in[16], *G_d = (const float*)d_in[17];
    const float* P_1 = (const float*)d_in[18], *P_2 = (const float*)d_in[19];
    const float* D_1 = (const float*)d_in[20], *D_2 = (const float*)d_in[21];
    const float* gamma_s = (const float*)d_in[22], *gamma_p = (const float*)d_in[23], *gamma_d = (const float*)d_in[24];
    const float* sw_a = (const float*)d_in[25], *sw_b = (const float*)d_in[26];

    const i64 S = (i64)NA * F;
    float* res0 = (float*)d_ws;                        // S floats (f32 channel 0)
    unsigned short* resb = (unsigned short*)(res0 + S);// 3S ushorts (bf16 ch 1..3)
    float* inp  = (float*)(resb + 3 * S);              // S floats
    unsigned short* Q = (unsigned short*)(inp + S);    // 8S ushorts
    float* rec  = (float*)(Q + 8 * S);                 // NE*RECW floats (aliased by part)
    unsigned short* part = (unsigned short*)rec;       // 8S ushorts <= NE*RECW floats
    int* fill   = (int*)(rec + (i64)NE * RECW);        // NA ints
    int* idx    = fill + NA + 8;                       // NA*QCAP ints
    unsigned short* Wb = (unsigned short*)(idx + NA * QCAP);  // 317440 bf16 (weights+G)

    const int NT = (NA + 31) / 32;   // 157

    // node 1: weights + G tables -> bf16, zero fill[]
    wconv<<<dim3(32, 13), 256, 0, stream>>>(rm_W1, rm_W2, rm_W3, rl_W1, rl_W2, rl_W3,
                                            P_1, P_2, D_1, D_2, G_s, G_p, G_d, Wb, fill);

    // node 2: residual MLP (4 channels, y=0..3; ch0->f32 res0, ch1-3->bf16 resb)
    //         + fused edge-prep (y=4..6)
    mlp3_mfma<0,1,2,1,1,1,4,1><<<dim3(NT, 7), 256, 0, stream>>>(
        x_tilde,
        Wb + 0, rm_b1, Wb + 65536, rm_b2, Wb + 131072, rm_b3,
        res0, resb, sw_a, sw_b, NA,
        xyz, nbrs, fill, idx, gamma_s, gamma_p, gamma_d, rec);

    // node 3: moments -> inp = res0 + q_s, Q[m] (bf16)
    q_gather<<<NA, 256, 0, stream>>>(rec, idx, fill, res0, resb,
                                     (const unsigned*)(Wb + 311296), inp, Q);

    // node 4: bilinear P/D contraction -> part[m] (bf16), 64-atom tiles
    bilinear_mfma<<<dim3((NA + 63) / 64, 8), 256, 0, stream>>>(
        Q, Wb + 245760, Wb + 262144, Wb + 278528, Wb + 294912, part, NA);

    // node 5: final MLP (inp + sum_m part -> out), M=16 (313 blocks)
    mlpf16<<<(NA + 15) / 16, 256, 0, stream>>>(
        inp, part,
        Wb + 196608, rl_b1, Wb + 212992, rl_b2, Wb + 229376, rl_b3,
        (float*)d_out, sw_a, sw_b, NA);
}

// Round 17
// 72.964 us; speedup vs baseline: 1.1110x; 1.0079x over previous
//
#include <hip/hip_runtime.h>
#include <hip/hip_bf16.h>
#include <math.h>

#define NA 5000
#define NE 100000
#define F 128
#define KB 16
#define RCUT 5.0f
#define RECW 28   // words per edge record: i1, ux,uy,uz, 24 bf16-pair words
#define QCAP 40   // per-atom index bucket capacity (mean active deg ~6)

typedef long long i64;
typedef __attribute__((ext_vector_type(8))) short bf16x8;   // 8 bf16 = 4 VGPRs
typedef __attribute__((ext_vector_type(4))) float f32x4;

struct WSrc { const float* p[10]; };   // rl_W1..3, P1, P2, D1, D2, G_s, G_p, G_d

__device__ __forceinline__ float swish_f(float t, float a, float b){
    return a * t / (1.0f + __expf(-b * t));
}
__device__ __forceinline__ float bf2f(unsigned short u){
    return __uint_as_float(((unsigned)u) << 16);
}
__device__ __forceinline__ unsigned short f2bf(float x){
    unsigned b = __float_as_uint(x);
    return (unsigned short)((b + 0x8000u) >> 16);
}
__device__ __forceinline__ unsigned pack2(float a, float b){
    return (unsigned)f2bf(a) | ((unsigned)f2bf(b) << 16);
}
// XOR swizzle for row-major [R][128] bf16 LDS tile (256 B/row).
__device__ __forceinline__ int swz(int row, int byte_in_row){
    return row * 256 + (byte_in_row ^ ((row & 7) << 4));
}

// ---------------------------------------------------------------------------
// MFMA GEMM stage (bf16 weights): acc += act(MT*16 x 128, LDS swizzled) x W^T
// ---------------------------------------------------------------------------
template<int MT>
__device__ __forceinline__ void gemm_stage(const unsigned short* __restrict__ Wb,
                                           const short* act_lds, f32x4 (&acc)[MT][2],
                                           int lane, int wave)
{
    bf16x8 B[2][4], A[MT][4];
    const int cl = lane & 15, kh = lane >> 4;
    #pragma unroll
    for (int ntl = 0; ntl < 2; ++ntl){
        const unsigned short* wp = Wb + (i64)(wave * 32 + ntl * 16 + cl) * F + kh * 8;
        #pragma unroll
        for (int kb = 0; kb < 4; ++kb)
            B[ntl][kb] = *(const bf16x8*)(wp + kb * 32);
    }
    #pragma unroll
    for (int mt = 0; mt < MT; ++mt){
        int row = mt * 16 + cl;
        #pragma unroll
        for (int kb = 0; kb < 4; ++kb)
            A[mt][kb] = *(const bf16x8*)((const char*)act_lds + swz(row, kb * 64 + kh * 16));
    }
    #pragma unroll
    for (int mt = 0; mt < MT; ++mt)
        #pragma unroll
        for (int ntl = 0; ntl < 2; ++ntl)
            #pragma unroll
            for (int kb = 0; kb < 4; ++kb)
                acc[mt][ntl] = __builtin_amdgcn_mfma_f32_16x16x32_bf16(
                    A[mt][kb], B[ntl][kb], acc[mt][ntl], 0, 0, 0);
}

// epilogue: z = acc + bias (+resid), swish -> bf16 -> act_lds
template<int MT>
__device__ __forceinline__ void epi_lds(f32x4 acc[MT][2], const float* __restrict__ bc,
                                        const float* resid_lds, int use_resid,
                                        float aS, float bS, short* act_lds,
                                        int lane, int wave)
{
    const int cl = lane & 15, r4 = (lane >> 4) * 4;
    #pragma unroll
    for (int ntl = 0; ntl < 2; ++ntl){
        int col = wave * 32 + ntl * 16 + cl;
        float bv = bc[col];
        #pragma unroll
        for (int mt = 0; mt < MT; ++mt){
            #pragma unroll
            for (int j = 0; j < 4; ++j){
                int row = mt * 16 + r4 + j;
                float z = acc[mt][ntl][j] + bv;
                if (use_resid) z += resid_lds[row * 132 + col];
                z = swish_f(z, aS, bS);
                *(short*)((char*)act_lds + swz(row, col * 2)) = (short)f2bf(z);
            }
        }
    }
}

// ---------------------------------------------------------------------------
// Edge-record builder: slot = edge id, idx bucket per owner atom.
// ---------------------------------------------------------------------------
__device__ __forceinline__ void basis16(float r, float g, float fcut, float* b){
    const float C[KB] = {1.f,15.f,105.f,455.f,1365.f,3003.f,5005.f,6435.f,
                         6435.f,5005.f,3003.f,1365.f,455.f,105.f,15.f,1.f};
    float e = __expf(-fmaxf(g, 0.f) * r);
    float one = 1.f - e;
    float ep = 1.f;
    #pragma unroll
    for (int k = 0; k < KB; ++k){ b[k] = C[k] * ep * fcut; ep *= e; }
    float op = 1.f;
    #pragma unroll
    for (int k = KB-1; k >= 0; --k){ b[k] *= op; op *= one; }
}

__device__ __forceinline__ void prep_edge_block(
    int ebid, const float* __restrict__ xyz, const int* __restrict__ nbrs,
    int* __restrict__ fill, int* __restrict__ idx,
    const float* __restrict__ gs, const float* __restrict__ gp,
    const float* __restrict__ gd, float* __restrict__ rec)
{
    int e = ebid * 256 + threadIdx.x;
    if (e >= NE) return;
    int i0 = nbrs[2*e], i1 = nbrs[2*e+1];
    float dx = xyz[3*i1]   - xyz[3*i0];
    float dy = xyz[3*i1+1] - xyz[3*i0+1];
    float dz = xyz[3*i1+2] - xyz[3*i0+2];
    float r2 = dx*dx + dy*dy + dz*dz + 3e-15f;
    float r = sqrtf(r2);
    if (r >= RCUT) return;
    int slot = atomicAdd(&fill[i0], 1);
    if (slot < QCAP) idx[i0 * QCAP + slot] = e;   // slot = edge id
    float* R = rec + (i64)e * RECW;
    float ir = 1.f / r;
    R[0] = __int_as_float(i1);
    R[1] = dx * ir; R[2] = dy * ir; R[3] = dz * ir;
    float fcut = __expf(-r2 / ((RCUT - r) * (RCUT + r)));
    float bs[KB], bp[KB], bd[KB];
    basis16(r, gs[0], fcut, bs);
    basis16(r, gp[0], fcut, bp);
    basis16(r, gd[0], fcut, bd);
    unsigned* RW = (unsigned*)(R + 4);
    #pragma unroll
    for (int k = 0; k < 8; ++k) RW[k]      = pack2(bs[2*k], bs[2*k+1]);
    #pragma unroll
    for (int k = 0; k < 8; ++k) RW[8 + k]  = pack2(bp[2*k], bp[2*k+1]);
    #pragma unroll
    for (int k = 0; k < 8; ++k) RW[16 + k] = pack2(bd[2*k], bd[2*k+1]);
}

// Convert one of the 10 deferred tensors (ride-along in node 2).
// cb in [0,157): tensor t = cb % 10, chunk = cb / 10 (0..15), stride 16*256.
__device__ __forceinline__ void wconv_rest_block(int cb, WSrc ws,
                                                 unsigned short* __restrict__ dst)
{
    int t = cb % 10;
    int chunk = cb / 10;
    if (chunk >= 16) return;
    const float* src = ws.p[t];
    i64 off; int sz;
    if      (t == 0){ off = 196608; sz = 16384; }
    else if (t == 1){ off = 212992; sz = 16384; }
    else if (t == 2){ off = 229376; sz = 16384; }
    else if (t == 3){ off = 245760; sz = 16384; }
    else if (t == 4){ off = 262144; sz = 16384; }
    else if (t == 5){ off = 278528; sz = 16384; }
    else if (t == 6){ off = 294912; sz = 16384; }
    else if (t == 7){ off = 311296; sz = 2048; }
    else if (t == 8){ off = 313344; sz = 2048; }
    else            { off = 315392; sz = 2048; }
    unsigned* d = (unsigned*)(dst + off);
    int pairs = sz >> 1;
    for (int p = chunk * 256 + threadIdx.x; p < pairs; p += 16 * 256)
        d[p] = pack2(src[2 * p], src[2 * p + 1]);
}

// ---------------------------------------------------------------------------
// Fused 3-stage MLP (rm path), MFMA core, M=32.
// PREP=1: blockIdx.y in [CH, CH+3) -> edge-prep rows; y == CH+3 -> deferred
// weight conversion row. RESB=1: ch0 -> f32 out, ch1..3 -> bf16 resb.
// ---------------------------------------------------------------------------
template<int S0, int S1, int S2, int ADD2, int ADD3, int PREP, int CH, int RESB>
__global__ __launch_bounds__(256)
void mlp3_mfma(const float* __restrict__ in,
               const unsigned short* __restrict__ W1b, const float* __restrict__ b1,
               const unsigned short* __restrict__ W2b, const float* __restrict__ b2,
               const unsigned short* __restrict__ W3b, const float* __restrict__ b3,
               float* __restrict__ out, unsigned short* __restrict__ resb,
               const float* __restrict__ sw_a, const float* __restrict__ sw_b, int n,
               const float* __restrict__ xyz, const int* __restrict__ nbrs,
               int* __restrict__ fill, int* __restrict__ idx,
               const float* __restrict__ gs, const float* __restrict__ gp,
               const float* __restrict__ gd, float* __restrict__ rec,
               WSrc ws, unsigned short* __restrict__ WbDst)
{
    if (PREP && blockIdx.y >= CH){
        int pb = blockIdx.y - CH;
        if (pb < 3){
            int ebid = pb * gridDim.x + blockIdx.x;
            if (ebid < (NE + 255) / 256)
                prep_edge_block(ebid, xyz, nbrs, fill, idx, gs, gp, gd, rec);
        } else {
            wconv_rest_block(blockIdx.x, ws, WbDst);
        }
        return;
    }

    __shared__ short act_lds[32 * 128];     // swizzled bf16 activations
    __shared__ float resid_lds[32 * 132];   // padded f32 residual copy
    const int tid = threadIdx.x;
    const int lane = tid & 63, wave = tid >> 6;
    const int c = blockIdx.y;
    const int a0 = blockIdx.x * 32;
    const i64 S = (i64)NA * F;

    const unsigned short* Wc1 = W1b + (i64)c * F * F;
    const unsigned short* Wc2 = W2b + (i64)c * F * F;
    const unsigned short* Wc3 = W3b + (i64)c * F * F;
    const float* bc1 = b1 + c * F;
    const float* bc2 = b2 + c * F;
    const float* bc3 = b3 + c * F;

    { // stage input: resid (f32) + swish_S0 -> bf16 act
        float aS = sw_a[S0], bS = sw_b[S0];
        #pragma unroll
        for (int it = 0; it < 4; ++it){
            int ch = tid + it * 256;         // 1024 float4-chunks
            int row = ch >> 5, j4 = ch & 31;
            int g = a0 + row;
            float4 v = make_float4(0.f, 0.f, 0.f, 0.f);
            if (g < n) v = *(const float4*)(in + (i64)g * F + j4 * 4);
            *(float4*)&resid_lds[row * 132 + j4 * 4] = v;
            uint2 p;
            p.x = pack2(swish_f(v.x, aS, bS), swish_f(v.y, aS, bS));
            p.y = pack2(swish_f(v.z, aS, bS), swish_f(v.w, aS, bS));
            *(uint2*)((char*)act_lds + swz(row, j4 * 8)) = p;
        }
    }
    __syncthreads();

    f32x4 acc[2][2];
    #pragma unroll
    for (int a = 0; a < 2; ++a){ acc[a][0] = (f32x4){0,0,0,0}; acc[a][1] = (f32x4){0,0,0,0}; }
    gemm_stage<2>(Wc1, act_lds, acc, lane, wave);
    __syncthreads();
    epi_lds<2>(acc, bc1, resid_lds, 0, sw_a[S1], sw_b[S1], act_lds, lane, wave);
    __syncthreads();

    #pragma unroll
    for (int a = 0; a < 2; ++a){ acc[a][0] = (f32x4){0,0,0,0}; acc[a][1] = (f32x4){0,0,0,0}; }
    gemm_stage<2>(Wc2, act_lds, acc, lane, wave);
    __syncthreads();
    epi_lds<2>(acc, bc2, resid_lds, ADD2, sw_a[S2], sw_b[S2], act_lds, lane, wave);
    __syncthreads();

    #pragma unroll
    for (int a = 0; a < 2; ++a){ acc[a][0] = (f32x4){0,0,0,0}; acc[a][1] = (f32x4){0,0,0,0}; }
    gemm_stage<2>(Wc3, act_lds, acc, lane, wave);
    {
        const int cl = lane & 15, r4 = (lane >> 4) * 4;
        #pragma unroll
        for (int ntl = 0; ntl < 2; ++ntl){
            int col = wave * 32 + ntl * 16 + cl;
            float bv = bc3[col];
            #pragma unroll
            for (int mt = 0; mt < 2; ++mt){
                #pragma unroll
                for (int j = 0; j < 4; ++j){
                    int row = mt * 16 + r4 + j;
                    int g = a0 + row;
                    if (g >= n) continue;
                    float z = acc[mt][ntl][j] + bv;
                    if (ADD3) z += resid_lds[row * 132 + col];
                    if (RESB && c > 0)
                        resb[(i64)(c - 1) * S + (i64)g * F + col] = f2bf(z);
                    else
                        out[(i64)g * F + col] = z;
                }
            }
        }
    }
}

// ---------------------------------------------------------------------------
// Final MLP, M=16 (313 blocks): inp + sum_m part -> 3-stage rl MLP -> out.
// ---------------------------------------------------------------------------
__global__ __launch_bounds__(256)
void mlpf16(const float* __restrict__ inp, const unsigned short* __restrict__ part,
            const unsigned short* __restrict__ W1b, const float* __restrict__ b1,
            const unsigned short* __restrict__ W2b, const float* __restrict__ b2,
            const unsigned short* __restrict__ W3b, const float* __restrict__ b3,
            float* __restrict__ out,
            const float* __restrict__ sw_a, const float* __restrict__ sw_b, int n)
{
    __shared__ short act_lds[16 * 128];
    __shared__ float resid_lds[16 * 132];
    const int tid = threadIdx.x;
    const int lane = tid & 63, wave = tid >> 6;
    const int a0 = blockIdx.x * 16;
    const i64 S = (i64)NA * F;
    const int cl = lane & 15, r4 = (lane >> 4) * 4;

    { // stage: z = inp + sum_m part -> resid; act = swish_3(z)
        float aS = sw_a[3], bS = sw_b[3];
        #pragma unroll
        for (int it = 0; it < 2; ++it){
            int ch = tid + it * 256;          // 512 float4-chunks
            int row = ch >> 5, j4 = ch & 31;
            int g = a0 + row;
            float4 v = make_float4(0.f, 0.f, 0.f, 0.f);
            if (g < n){
                v = *(const float4*)(inp + (i64)g * F + j4 * 4);
                #pragma unroll
                for (int m = 0; m < 8; ++m){
                    ushort4 u = *(const ushort4*)(part + (i64)m * S + (i64)g * F + j4 * 4);
                    v.x += bf2f(u.x); v.y += bf2f(u.y);
                    v.z += bf2f(u.z); v.w += bf2f(u.w);
                }
            }
            *(float4*)&resid_lds[row * 132 + j4 * 4] = v;
            uint2 p;
            p.x = pack2(swish_f(v.x, aS, bS), swish_f(v.y, aS, bS));
            p.y = pack2(swish_f(v.z, aS, bS), swish_f(v.w, aS, bS));
            *(uint2*)((char*)act_lds + swz(row, j4 * 8)) = p;
        }
    }
    __syncthreads();

    f32x4 acc[1][2];
    acc[0][0] = (f32x4){0,0,0,0}; acc[0][1] = (f32x4){0,0,0,0};
    gemm_stage<1>(W1b, act_lds, acc, lane, wave);
    __syncthreads();
    epi_lds<1>(acc, b1, resid_lds, 0, sw_a[4], sw_b[4], act_lds, lane, wave);
    __syncthreads();

    acc[0][0] = (f32x4){0,0,0,0}; acc[0][1] = (f32x4){0,0,0,0};
    gemm_stage<1>(W2b, act_lds, acc, lane, wave);
    __syncthreads();
    epi_lds<1>(acc, b2, resid_lds, 1, sw_a[5], sw_b[5], act_lds, lane, wave);
    __syncthreads();

    acc[0][0] = (f32x4){0,0,0,0}; acc[0][1] = (f32x4){0,0,0,0};
    gemm_stage<1>(W3b, act_lds, acc, lane, wave);
    {
        #pragma unroll
        for (int ntl = 0; ntl < 2; ++ntl){
            int col = wave * 32 + ntl * 16 + cl;
            float bv = b3[col];
            #pragma unroll
            for (int j = 0; j < 4; ++j){
                int g = a0 + r4 + j;
                if (g >= n) continue;
                out[(i64)g * F + col] = acc[0][ntl][j] + bv;
            }
        }
    }
}

// ---------------------------------------------------------------------------
// Bilinear, MFMA core (bf16 W), 64-atom tiles.
// ---------------------------------------------------------------------------
__global__ __launch_bounds__(256)
void bilinear_mfma(const unsigned short* __restrict__ Q,
                   const unsigned short* __restrict__ P1b, const unsigned short* __restrict__ P2b,
                   const unsigned short* __restrict__ D1b, const unsigned short* __restrict__ D2b,
                   unsigned short* __restrict__ part, int n)
{
    __shared__ short act_lds[64 * 128];
    const int tid = threadIdx.x;
    const int lane = tid & 63, wave = tid >> 6;
    const int m = blockIdx.y;
    const int a0 = blockIdx.x * 64;
    const i64 S = (i64)NA * F;
    const unsigned short* M1 = (m < 3) ? P1b : D1b;
    const unsigned short* M2 = (m < 3) ? P2b : D2b;
    const unsigned short* A = Q + (i64)m * S;

    #pragma unroll
    for (int it = 0; it < 4; ++it){
        int ch = tid + it * 256;          // 1024 16B-chunks
        int row = ch >> 4, o16 = ch & 15;
        int g = a0 + row;
        uint4 v = make_uint4(0u, 0u, 0u, 0u);
        if (g < n) v = *(const uint4*)(A + (i64)g * F + o16 * 8);
        *(uint4*)((char*)act_lds + swz(row, o16 * 16)) = v;
    }
    __syncthreads();

    f32x4 acc1[4][2], acc2[4][2];
    #pragma unroll
    for (int a = 0; a < 4; ++a){
        acc1[a][0] = (f32x4){0,0,0,0}; acc1[a][1] = (f32x4){0,0,0,0};
        acc2[a][0] = (f32x4){0,0,0,0}; acc2[a][1] = (f32x4){0,0,0,0};
    }
    gemm_stage<4>(M1, act_lds, acc1, lane, wave);
    gemm_stage<4>(M2, act_lds, acc2, lane, wave);

    const int cl = lane & 15, r4 = (lane >> 4) * 4;
    #pragma unroll
    for (int ntl = 0; ntl < 2; ++ntl){
        int col = wave * 32 + ntl * 16 + cl;
        #pragma unroll
        for (int mt = 0; mt < 4; ++mt){
            #pragma unroll
            for (int j = 0; j < 4; ++j){
                int g = a0 + mt * 16 + r4 + j;
                if (g >= n) continue;
                part[(i64)m * S + (i64)g * F + col] =
                    f2bf(acc1[mt][ntl][j] * acc2[mt][ntl][j]);
            }
        }
    }
}

// ---------------------------------------------------------------------------
// Node 1: rm weights only (3 tensors) -> bf16, + zero fill[]
// ---------------------------------------------------------------------------
__global__ __launch_bounds__(256)
void wconv(const float* s0, const float* s1, const float* s2,
           unsigned short* __restrict__ dst, int* __restrict__ fillz)
{
    int t = blockIdx.y;
    if (t == 0){
        for (int i = blockIdx.x * 256 + threadIdx.x; i < NA; i += 32 * 256)
            fillz[i] = 0;
    }
    const float* src; i64 off;
    if      (t == 0){ src = s0; off = 0; }
    else if (t == 1){ src = s1; off = 65536; }
    else            { src = s2; off = 131072; }
    unsigned* d = (unsigned*)(dst + off);
    const int pairs = 32768;
    for (int p = blockIdx.x * 256 + threadIdx.x; p < pairs; p += 32 * 256)
        d[p] = pack2(src[2 * p], src[2 * p + 1]);
}

// ---------------------------------------------------------------------------
// Moment gather v5 (r12/r14 form)
// ---------------------------------------------------------------------------
__global__ __launch_bounds__(256)
void q_gather(const float* __restrict__ rec, const int* __restrict__ idx,
              const int* __restrict__ fill,
              const float* __restrict__ res0, const unsigned short* __restrict__ resb,
              const unsigned* __restrict__ Gb,   // 3 x [F][8] u32 (packed bf16)
              float* __restrict__ inp, unsigned short* __restrict__ Q)
{
    const int n = blockIdx.x;
    const int tid = threadIdx.x;
    const int s = tid >> 7;
    const int f = tid & 127;
    const int lane = tid & 63, wave = tid >> 6;
    const i64 S = (i64)NA * F;

    __shared__ int   idx_s[QCAP];
    __shared__ float recs[QCAP * RECW];             // 4.5 KB
    __shared__ __align__(16) char upool[12288];     // D (12KB bf16) / red (9.2KB f32)
    unsigned short* D = (unsigned short*)upool;     // [3][16][128]
    float* red = (float*)upool;                     // [2][9][128]

    if (tid < QCAP) idx_s[tid] = idx[n * QCAP + tid];
    const int cnt = min(fill[n], QCAP);
    __syncthreads();
    for (int w = tid; w < cnt * RECW; w += 256){
        int j = w / RECW, o = w - j * RECW;
        recs[w] = rec[(i64)idx_s[j] * RECW + o];
    }
    __syncthreads();

    float qs = 0.f;
    float qp0=0.f, qp1=0.f, qp2=0.f;
    float qd0=0.f, qd1=0.f, qd2=0.f, qd3=0.f, qd4=0.f;
    const float s3 = 1.7320508075688772f;
    const int cl = lane & 15, kh = lane >> 4;

    for (int base = 0; base < cnt; base += 16){
        // --- MFMA bern x G contraction for this chunk ---
        {
            int er = base + cl; if (er >= QCAP) er = 0;
            bf16x8 A[3];
            #pragma unroll
            for (int ch = 0; ch < 3; ++ch){
                if (kh < 2){
                    const unsigned* bw = (const unsigned*)&recs[er * RECW + 4];
                    union { uint4 u; bf16x8 h; } cv;
                    cv.u = *(const uint4*)(bw + ch * 8 + kh * 4);
                    A[ch] = cv.h;
                } else {
                    A[ch] = (bf16x8){0,0,0,0,0,0,0,0};
                }
            }
            #pragma unroll
            for (int ch = 0; ch < 3; ++ch){
                #pragma unroll
                for (int ct = 0; ct < 2; ++ct){
                    int fc = wave * 32 + ct * 16 + cl;
                    bf16x8 B;
                    if (kh < 2){
                        union { uint4 u; bf16x8 h; } cv;
                        cv.u = *(const uint4*)(Gb + (i64)ch * F * 8 + fc * 8 + kh * 4);
                        B = cv.h;
                    } else {
                        B = (bf16x8){0,0,0,0,0,0,0,0};
                    }
                    f32x4 z = (f32x4){0.f, 0.f, 0.f, 0.f};
                    z = __builtin_amdgcn_mfma_f32_16x16x32_bf16(A[ch], B, z, 0, 0, 0);
                    #pragma unroll
                    for (int j = 0; j < 4; ++j)
                        D[ch * 2048 + (kh * 4 + j) * 128 + fc] = f2bf(z[j]);
                }
            }
        }
        __syncthreads();

        // --- f-major accumulation with 1-deep a-row prefetch ---
        const int mrec = min(16, cnt - base);
        int j = s;
        float a1n = 0.f, a2n = 0.f, a3n = 0.f;
        if (j < mrec){
            int i1 = __float_as_int(recs[(base + j) * RECW]);
            a1n = bf2f(resb[(i64)i1 * F + f]);
            a2n = bf2f(resb[S + (i64)i1 * F + f]);
            a3n = bf2f(resb[2 * S + (i64)i1 * F + f]);
        }
        for (; j < mrec; j += 2){
            float a1 = a1n, a2 = a2n, a3 = a3n;
            int jn = j + 2;
            if (jn < mrec){
                int i1 = __float_as_int(recs[(base + jn) * RECW]);
                a1n = bf2f(resb[(i64)i1 * F + f]);
                a2n = bf2f(resb[S + (i64)i1 * F + f]);
                a3n = bf2f(resb[2 * S + (i64)i1 * F + f]);
            }
            const float* R = &recs[(base + j) * RECW];
            float ux = R[1], uy = R[2], uz = R[3];
            float ds = bf2f(D[0 * 2048 + j * 128 + f]);
            float dp = bf2f(D[1 * 2048 + j * 128 + f]);
            float dd = bf2f(D[2 * 2048 + j * 128 + f]);
            qs += a1 * ds;
            float tp = a2 * dp;
            qp0 += tp * uy; qp1 += tp * uz; qp2 += tp * ux;
            float td = a3 * dd;
            qd0 += td * (s3 * ux * uy);
            qd1 += td * (s3 * uy * uz);
            qd2 += td * (1.5f * uz * uz - 0.5f);
            qd3 += td * (s3 * ux * uz);
            qd4 += td * (0.5f * s3 * (ux*ux - uy*uy));
        }
        __syncthreads();
    }

    red[(s * 9 + 0) * 128 + f] = qs;
    red[(s * 9 + 1) * 128 + f] = qp0; red[(s * 9 + 2) * 128 + f] = qp1;
    red[(s * 9 + 3) * 128 + f] = qp2;
    red[(s * 9 + 4) * 128 + f] = qd0; red[(s * 9 + 5) * 128 + f] = qd1;
    red[(s * 9 + 6) * 128 + f] = qd2; red[(s * 9 + 7) * 128 + f] = qd3;
    red[(s * 9 + 8) * 128 + f] = qd4;
    __syncthreads();
    if (s == 0){
        float sums[9];
        #pragma unroll
        for (int i = 0; i < 9; ++i)
            sums[i] = red[(0 * 9 + i) * 128 + f] + red[(1 * 9 + i) * 128 + f];
        inp[(i64)n*F + f] = res0[(i64)n*F + f] + sums[0];
        #pragma unroll
        for (int mm = 0; mm < 8; ++mm)
            Q[(i64)mm * S + (i64)n*F + f] = f2bf(sums[1 + mm]);
    }
}

// ---------------------------------------------------------------------------
extern "C" void kernel_launch(void* const* d_in, const int* in_sizes, int n_in,
                              void* d_out, int out_size, void* d_ws, size_t ws_size,
                              hipStream_t stream)
{
    const float* xyz     = (const float*)d_in[0];
    const float* x_tilde = (const float*)d_in[1];
    const int*   nbrs    = (const int*)d_in[2];
    const float* rm_W1 = (const float*)d_in[3],  *rm_b1 = (const float*)d_in[4];
    const float* rm_W2 = (const float*)d_in[5],  *rm_b2 = (const float*)d_in[6];
    const float* rm_W3 = (const float*)d_in[7],  *rm_b3 = (const float*)d_in[8];
    const float* rl_W1 = (const float*)d_in[9],  *rl_b1 = (const float*)d_in[10];
    const float* rl_W2 = (const float*)d_in[11], *rl_b2 = (const float*)d_in[12];
    const float* rl_W3 = (const float*)d_in[13], *rl_b3 = (const float*)d_in[14];
    const float* G_s = (const float*)d_in[15], *G_p = (const float*)d_in[16], *G_d = (const float*)d_in[17];
    const float* P_1 = (const float*)d_in[18], *P_2 = (const float*)d_in[19];
    const float* D_1 = (const float*)d_in[20], *D_2 = (const float*)d_in[21];
    const float* gamma_s = (const float*)d_in[22], *gamma_p = (const float*)d_in[23], *gamma_d = (const float*)d_in[24];
    const float* sw_a = (const float*)d_in[25], *sw_b = (const float*)d_in[26];

    const i64 S = (i64)NA * F;
    float* res0 = (float*)d_ws;                        // S floats (f32 channel 0)
    unsigned short* resb = (unsigned short*)(res0 + S);// 3S ushorts (bf16 ch 1..3)
    float* inp  = (float*)(resb + 3 * S);              // S floats
    unsigned short* Q = (unsigned short*)(inp + S);    // 8S ushorts
    float* rec  = (float*)(Q + 8 * S);                 // NE*RECW floats (aliased by part)
    unsigned short* part = (unsigned short*)rec;       // 8S ushorts <= NE*RECW floats
    int* fill   = (int*)(rec + (i64)NE * RECW);        // NA ints
    int* idx    = fill + NA + 8;                       // NA*QCAP ints
    unsigned short* Wb = (unsigned short*)(idx + NA * QCAP);  // 317440 bf16 (weights+G)

    const int NT = (NA + 31) / 32;   // 157

    WSrc ws;
    ws.p[0] = rl_W1; ws.p[1] = rl_W2; ws.p[2] = rl_W3;
    ws.p[3] = P_1;   ws.p[4] = P_2;   ws.p[5] = D_1;  ws.p[6] = D_2;
    ws.p[7] = G_s;   ws.p[8] = G_p;   ws.p[9] = G_d;

    // node 1: rm weights -> bf16, zero fill[] (rest converted inside node 2)
    wconv<<<dim3(32, 3), 256, 0, stream>>>(rm_W1, rm_W2, rm_W3, Wb, fill);

    // node 2: residual MLP (y=0..3) + edge-prep (y=4..6) + deferred wconv (y=7)
    mlp3_mfma<0,1,2,1,1,1,4,1><<<dim3(NT, 8), 256, 0, stream>>>(
        x_tilde,
        Wb + 0, rm_b1, Wb + 65536, rm_b2, Wb + 131072, rm_b3,
        res0, resb, sw_a, sw_b, NA,
        xyz, nbrs, fill, idx, gamma_s, gamma_p, gamma_d, rec,
        ws, Wb);

    // node 3: moments -> inp = res0 + q_s, Q[m] (bf16)
    q_gather<<<NA, 256, 0, stream>>>(rec, idx, fill, res0, resb,
                                     (const unsigned*)(Wb + 311296), inp, Q);

    // node 4: bilinear P/D contraction -> part[m] (bf16), 64-atom tiles
    bilinear_mfma<<<dim3((NA + 63) / 64, 8), 256, 0, stream>>>(
        Q, Wb + 245760, Wb + 262144, Wb + 278528, Wb + 294912, part, NA);

    // node 5: final MLP (inp + sum_m part -> out), M=16 (313 blocks)
    mlpf16<<<(NA + 15) / 16, 256, 0, stream>>>(
        inp, part,
        Wb + 196608, rl_b1, Wb + 212992, rl_b2, Wb + 229376, rl_b3,
        (float*)d_out, sw_a, sw_b, NA);
}